// Round 2
// baseline (1116.956 us; speedup 1.0000x reference)
//
#include <hip/hip_runtime.h>
#include <hip/hip_bf16.h>
#include <cstdint>

#define NN   100000
#define TT   4
#define EE   250000
#define LL   2
#define NCH  49            // ceil(NN/2048)
#define EPN  (EE + NN)     // 350000
#define N64  ((size_t)NN * 64)
#define CHK  25088         // node-chunk for z staging (4 chunks, 128-divisible)

typedef unsigned short ushort_t;
typedef __attribute__((ext_vector_type(8))) short bf16x8;
typedef __attribute__((ext_vector_type(16))) float floatx16;

static __device__ __forceinline__ float gelu_exact(float v) {
    return 0.5f * v * (1.0f + erff(v * 0.7071067811865476f));
}
static __device__ __forceinline__ float wave_sum64(float v) {
    #pragma unroll
    for (int m = 32; m; m >>= 1) v += __shfl_xor(v, m, 64);
    return v;
}
// fp32 -> bf16 round-to-nearest-even (finite inputs only)
static __device__ __forceinline__ ushort_t f2bf(float f) {
    unsigned u = __float_as_uint(f);
    u += 0x7FFFu + ((u >> 16) & 1u);
    return (ushort_t)(u >> 16);
}
static __device__ __forceinline__ float bf2f(ushort_t h) {
    return __uint_as_float((unsigned)h << 16);
}

// ---------------------------------------------------------------------------
// Prep: all GEMM B-operands as TRANSPOSED split-bf16 planes [n][k]:
//  wcollT[l][col][d]  (K=64)   col = t*8+side*4+h, from W·a dot products
//  linwT[c][k]        (K=256)  from lin_w[k][c]
//  bprojT[l][c][kidx] (K=1024) kidx = t*256+h*64+d, val 0.25*W_src[l,t,d,h*64+c]
//  bsum[l][c] = sum_t conv_bias
// ---------------------------------------------------------------------------
__global__ __launch_bounds__(256) void k_prep(
    const float* __restrict__ Wsrc, const float* __restrict__ Wdst,
    const float* __restrict__ asrc, const float* __restrict__ adst,
    const float* __restrict__ cb, const float* __restrict__ lin_w,
    ushort_t* __restrict__ wcTh, ushort_t* __restrict__ wcTl,
    ushort_t* __restrict__ lwTh, ushort_t* __restrict__ lwTl,
    ushort_t* __restrict__ bpTh, ushort_t* __restrict__ bpTl,
    float* __restrict__ bsum)
{
    int id = blockIdx.x * 256 + threadIdx.x;   // grid = 131072 exactly
    {   // bprojT: id = ((((l*4+t)*4+h)*64 + c)*64 + d)
        int d = id & 63;
        int c = (id >> 6) & 63;
        int h = (id >> 12) & 3;
        int t = (id >> 14) & 3;
        int l = (id >> 16) & 1;
        float v = 0.25f * Wsrc[(((l * 4 + t) * 64 + d) * 256) + h * 64 + c];
        int dst = (l * 64 + c) * 1024 + (t * 256 + h * 64 + d);
        ushort_t hh = f2bf(v);
        bpTh[dst] = hh;
        bpTl[dst] = f2bf(v - bf2f(hh));
    }
    if (id < LL * 64 * 64) {   // wcollT
        int d   = id & 63;
        int col = (id >> 6) & 63;
        int l   = (id >> 12) & 1;
        int t = col >> 3, side = (col >> 2) & 1, h = col & 3;
        const float* W = side ? Wdst : Wsrc;
        const float* a = side ? adst : asrc;
        int wb = ((l * 4 + t) * 64 + d) * 256 + h * 64;
        int ab = ((l * 4 + t) * 4 + h) * 64;
        float s = 0.f;
        #pragma unroll 8
        for (int c2 = 0; c2 < 64; ++c2) s = fmaf(W[wb + c2], a[ab + c2], s);
        int dst = (l * 64 + col) * 64 + d;
        ushort_t hh = f2bf(s);
        wcTh[dst] = hh;
        wcTl[dst] = f2bf(s - bf2f(hh));
    }
    if (id < 64 * 256) {       // linwT: c = id>>8, k = id&255
        int k = id & 255, c = id >> 8;
        float v = lin_w[k * 64 + c];
        ushort_t hh = f2bf(v);
        lwTh[c * 256 + k] = hh;
        lwTl[c * 256 + k] = f2bf(v - bf2f(hh));
    }
    if (id < LL * 64) {        // bias_sum
        int l = id >> 6, c = id & 63;
        float s = 0.f;
        for (int t = 0; t < TT; ++t) s += cb[(l * 4 + t) * 64 + c];
        bsum[id] = s;
    }
}

// ---------------------------------------------------------------------------
// CSR build (verified; k_scatter also records dst per slot)
// ---------------------------------------------------------------------------
__global__ void k_hist(const int* __restrict__ ei, int* __restrict__ cursor) {
    int id = blockIdx.x * 256 + threadIdx.x;
    if (id >= TT * EE) return;
    int t = id / EE, e = id - t * EE;
    int d = ei[(t * 2 + 1) * EE + e];
    atomicAdd(&cursor[t * NN + d], 1);
}

__global__ __launch_bounds__(256) void k_scan1(const int* __restrict__ deg,
                                               int* __restrict__ csum) {
    int b = blockIdx.x, t = b / NCH, cc = b - t * NCH;
    int tid = threadIdx.x;
    int base = cc * 2048 + tid * 8;
    int s = 0;
    #pragma unroll
    for (int i = 0; i < 8; ++i) {
        int idx = base + i;
        if (idx < NN) s += deg[t * NN + idx] + 1;   // +1: self loop
    }
    #pragma unroll
    for (int m = 32; m; m >>= 1) s += __shfl_xor(s, m, 64);
    __shared__ int ws4[4];
    int lane = tid & 63, wid = tid >> 6;
    if (lane == 0) ws4[wid] = s;
    __syncthreads();
    if (tid == 0) csum[b] = ws4[0] + ws4[1] + ws4[2] + ws4[3];
}

__global__ void k_scan2(const int* __restrict__ csum, int* __restrict__ cbase,
                        int* __restrict__ row_ptr) {
    int t = threadIdx.x;
    if (t >= TT) return;
    int base = 0;
    for (int c = 0; c < NCH; ++c) {
        cbase[t * NCH + c] = base;
        base += csum[t * NCH + c];
    }
    row_ptr[t * (NN + 1) + NN] = base;   // = EE + NN
}

__global__ __launch_bounds__(256) void k_scan3(int* __restrict__ cursor,
                                               const int* __restrict__ cbase,
                                               int* __restrict__ row_ptr) {
    int b = blockIdx.x, t = b / NCH, cc = b - t * NCH;
    int tid = threadIdx.x, lane = tid & 63, wid = tid >> 6;
    int base = cc * 2048 + tid * 8;
    int vals[8], ts = 0;
    #pragma unroll
    for (int i = 0; i < 8; ++i) {
        int idx = base + i;
        int v = (idx < NN) ? cursor[t * NN + idx] + 1 : 0;
        vals[i] = v; ts += v;
    }
    int v = ts;
    #pragma unroll
    for (int off = 1; off < 64; off <<= 1) {
        int u = __shfl_up(v, off, 64);
        if (lane >= off) v += u;
    }
    __shared__ int wt[4];
    if (lane == 63) wt[wid] = v;
    __syncthreads();
    int wbase = 0;
    for (int w = 0; w < wid; ++w) wbase += wt[w];
    int run = cbase[t * NCH + cc] + wbase + (v - ts);
    #pragma unroll
    for (int i = 0; i < 8; ++i) {
        int idx = base + i;
        if (idx < NN) {
            row_ptr[t * (NN + 1) + idx] = run;
            cursor[t * NN + idx] = run;     // becomes scatter write-head
        }
        run += vals[i];
    }
}

__global__ void k_scatter(const int* __restrict__ ei, int* __restrict__ cursor,
                          int* __restrict__ col, int* __restrict__ dstarr) {
    int id = blockIdx.x * 256 + threadIdx.x;
    if (id >= TT * EPN) return;
    int t = id / EPN, r = id - t * EPN;
    int s, d;
    if (r < EE) { s = ei[t * 2 * EE + r]; d = ei[(t * 2 + 1) * EE + r]; }
    else        { s = d = r - EE; }
    int pos = atomicAdd(&cursor[t * NN + d], 1);
    col[(size_t)t * EPN + pos] = s;
    dstarr[(size_t)t * EPN + pos] = d;
}

// ---------------------------------------------------------------------------
// Split-bf16 MFMA GEMM: C[N,64] = A[N,K] @ B[K,64] via 3 products
// (ah·bh + al·bh + ah·bl), mfma_f32_32x32x16_bf16.
// A: hi/lo planes [nrows][K] (lda=K), OR (FLAGS&8) raw fp32 [nrows][K] split
//    into hi/lo during LDS staging (bit-identical to the former k_split).
// B: hi/lo TRANSPOSED planes [64][ldb].
// Block: 256 thr / 4 waves; wave = 32 rows x 64 cols (2 col-tiles).
// Fragment layouts (verified m74/m101/m120-lineage):
//   A[m][k]: m=lane&31, k=(lane>>5)*8+j    B[k][n]: n=lane&31, same k
//   C/D: col=lane&31 (+32*ct), row=(reg&3)+8*(reg>>2)+4*(lane>>5)
// FLAGS bit1: gelu((v+bias)*0.25); bit3: A operand is fp32
// ---------------------------------------------------------------------------
template <int FLAGS>
__global__ __launch_bounds__(256, 4) void k_gemm_mx(
    const ushort_t* __restrict__ Ahi, const ushort_t* __restrict__ Alo,
    const ushort_t* __restrict__ Bhi, const ushort_t* __restrict__ Blo,
    int K, int ldb, int nrows,
    const float* __restrict__ bias, float* __restrict__ Cout)
{
    constexpr int KC = 32, LK = 40;          // LK shorts = 80 B row stride
    __shared__ ushort_t sAh[128 * LK], sAl[128 * LK];
    __shared__ ushort_t sBh[64 * LK],  sBl[64 * LK];
    const int tid = threadIdx.x;
    const int w = tid >> 6, ln = tid & 63;
    const int l31 = ln & 31, hl = ln >> 5;
    const int rowbase = blockIdx.x * 128;

    floatx16 accv[2];
    #pragma unroll
    for (int ct = 0; ct < 2; ++ct)
        #pragma unroll
        for (int r = 0; r < 16; ++r) accv[ct][r] = 0.f;

    for (int kc = 0; kc < K; kc += KC) {
        __syncthreads();
        // stage A: 128 rows x 32 k (8-k groups), both planes, 16B LDS stores
        #pragma unroll
        for (int i = 0; i < 2; ++i) {
            int f = tid + i * 256;           // 0..511
            int r = f >> 2, cg = f & 3;
            int row = rowbase + r;
            int so = r * LK + cg * 8;
            if (row < nrows) {
                size_t ga = (size_t)row * K + kc + cg * 8;
                if constexpr (FLAGS & 8) {
                    const float* Af = (const float*)Ahi;
                    float4 v0 = *(const float4*)(Af + ga);
                    float4 v1 = *(const float4*)(Af + ga + 4);
                    float vf[8] = {v0.x, v0.y, v0.z, v0.w, v1.x, v1.y, v1.z, v1.w};
                    unsigned hu[8], lu[8];
                    #pragma unroll
                    for (int q = 0; q < 8; ++q) {
                        ushort_t hh = f2bf(vf[q]);
                        hu[q] = hh;
                        lu[q] = f2bf(vf[q] - bf2f(hh));
                    }
                    uint4 H = make_uint4(hu[0] | (hu[1] << 16), hu[2] | (hu[3] << 16),
                                         hu[4] | (hu[5] << 16), hu[6] | (hu[7] << 16));
                    uint4 L = make_uint4(lu[0] | (lu[1] << 16), lu[2] | (lu[3] << 16),
                                         lu[4] | (lu[5] << 16), lu[6] | (lu[7] << 16));
                    *(uint4*)&sAh[so] = H;
                    *(uint4*)&sAl[so] = L;
                } else {
                    *(uint4*)&sAh[so] = *(const uint4*)(Ahi + ga);
                    *(uint4*)&sAl[so] = *(const uint4*)(Alo + ga);
                }
            } else {
                *(uint4*)&sAh[so] = make_uint4(0, 0, 0, 0);
                *(uint4*)&sAl[so] = make_uint4(0, 0, 0, 0);
            }
        }
        // stage B: 64 n-rows x 32 k, both planes
        {
            int r = tid >> 2, cg = tid & 3;
            size_t gb = (size_t)r * ldb + kc + cg * 8;
            int so = r * LK + cg * 8;
            *(uint4*)&sBh[so] = *(const uint4*)(Bhi + gb);
            *(uint4*)&sBl[so] = *(const uint4*)(Blo + gb);
        }
        __syncthreads();
        const int arow = (w << 5) + l31;
        #pragma unroll
        for (int s = 0; s < 2; ++s) {
            const int koff = (s << 4) + (hl << 3);
            bf16x8 ah  = *(const bf16x8*)&sAh[arow * LK + koff];
            bf16x8 al  = *(const bf16x8*)&sAl[arow * LK + koff];
            bf16x8 bh0 = *(const bf16x8*)&sBh[l31 * LK + koff];
            bf16x8 bl0 = *(const bf16x8*)&sBl[l31 * LK + koff];
            bf16x8 bh1 = *(const bf16x8*)&sBh[(32 + l31) * LK + koff];
            bf16x8 bl1 = *(const bf16x8*)&sBl[(32 + l31) * LK + koff];
            accv[0] = __builtin_amdgcn_mfma_f32_32x32x16_bf16(ah, bh0, accv[0], 0, 0, 0);
            accv[1] = __builtin_amdgcn_mfma_f32_32x32x16_bf16(ah, bh1, accv[1], 0, 0, 0);
            accv[0] = __builtin_amdgcn_mfma_f32_32x32x16_bf16(al, bh0, accv[0], 0, 0, 0);
            accv[1] = __builtin_amdgcn_mfma_f32_32x32x16_bf16(al, bh1, accv[1], 0, 0, 0);
            accv[0] = __builtin_amdgcn_mfma_f32_32x32x16_bf16(ah, bl0, accv[0], 0, 0, 0);
            accv[1] = __builtin_amdgcn_mfma_f32_32x32x16_bf16(ah, bl1, accv[1], 0, 0, 0);
        }
    }
    // epilogue
    #pragma unroll
    for (int ct = 0; ct < 2; ++ct) {
        int col = (ct << 5) + l31;
        float bv = (FLAGS & 2) ? bias[col] : 0.f;
        #pragma unroll
        for (int r = 0; r < 16; ++r) {
            int row = rowbase + (w << 5) + (r & 3) + ((r >> 2) << 3) + (hl << 2);
            if (row < nrows) {
                size_t idx = (size_t)row * 64 + col;
                float v = accv[ct][r];
                if (FLAGS & 2) v = gelu_exact((v + bv) * 0.25f);
                Cout[idx] = v;
            }
        }
    }
}

// ---------------------------------------------------------------------------
// Feature epilogue: x = gelu(LN(y + lin_b)) + l2norm(emb)  (fp32 only)
// ---------------------------------------------------------------------------
__global__ __launch_bounds__(256) void k_feat_post(
    const float* __restrict__ y, const float* __restrict__ lin_b,
    const float* __restrict__ ln_g, const float* __restrict__ ln_b,
    const float* __restrict__ emb, float* __restrict__ xout)
{
    int n = (blockIdx.x << 2) + (threadIdx.x >> 6);
    int c = threadIdx.x & 63;
    size_t base = (size_t)n * 64 + c;
    float v = y[base] + lin_b[c];
    float mean = wave_sum64(v) * 0.015625f;
    float t = v - mean;
    float var = wave_sum64(t * t) * 0.015625f;
    float vn = t * (1.0f / sqrtf(var + 1e-5f)) * ln_g[c] + ln_b[c];
    float g = gelu_exact(vn);
    float e = emb[base];
    float nrm = sqrtf(wave_sum64(e * e));
    float xv = g + e / fmaxf(nrm, 1e-12f);
    xout[base] = xv;
}

// ---------------------------------------------------------------------------
// Edge-parallel softmax numerator: one lane = one CSR slot.
// p[t][e][h] = exp(leakyrelu(s_all[src][t*8+h] + s_all[dst][t*8+4+h]))
// ---------------------------------------------------------------------------
__global__ __launch_bounds__(256) void k_edgep(
    const float* __restrict__ s_all, const int* __restrict__ col,
    const int* __restrict__ dstarr, float* __restrict__ parr)
{
    int i = blockIdx.x * 256 + threadIdx.x;
    int t = blockIdx.y;
    if (i >= EPN) return;
    size_t base = (size_t)t * EPN + i;
    int s = col[base], d = dstarr[base];
    const float4 a = *(const float4*)&s_all[(size_t)s * 64 + t * 8];
    const float4 b = *(const float4*)&s_all[(size_t)d * 64 + t * 8 + 4];
    float l0 = a.x + b.x, l1 = a.y + b.y;
    float l2 = a.z + b.z, l3 = a.w + b.w;
    l0 = l0 > 0.f ? l0 : 0.2f * l0;
    l1 = l1 > 0.f ? l1 : 0.2f * l1;
    l2 = l2 > 0.f ? l2 : 0.2f * l2;
    l3 = l3 > 0.f ? l3 : 0.2f * l3;
    float4 p = make_float4(__expf(l0), __expf(l1), __expf(l2), __expf(l3));
    *(float4*)&parr[base * 4] = p;
}

// ---------------------------------------------------------------------------
// Edge aggregation -> split-bf16 z planes for a NODE CHUNK, all 4 types.
// One wave per dst node.  z row layout: [n-n0][t*256 + h*64 + d]  (lda=1024)
// The z chunk (~100 MB) is a rotating buffer intended to stay L3-resident.
// ---------------------------------------------------------------------------
__global__ __launch_bounds__(256) void k_edge2(
    const float* __restrict__ x, const float* __restrict__ parr,
    const int* __restrict__ row_ptr, const int* __restrict__ col,
    ushort_t* __restrict__ zh, ushort_t* __restrict__ zl, int n0, int n1)
{
    int n = n0 + (blockIdx.x << 2) + (threadIdx.x >> 6);
    int lane = threadIdx.x & 63;
    if (n >= n1) return;
    #pragma unroll
    for (int t = 0; t < TT; ++t) {
        int rp0 = row_ptr[t * (NN + 1) + n];
        int rp1 = row_ptr[t * (NN + 1) + n + 1];
        const int* colt = col + (size_t)t * EPN;      // per-type segment base
        const float4* pt = (const float4*)parr + (size_t)t * EPN;
        float z0 = 0.f, z1 = 0.f, z2 = 0.f, z3 = 0.f;
        float S0 = 0.f, S1 = 0.f, S2 = 0.f, S3 = 0.f;
        #pragma unroll 2
        for (int e = rp0; e < rp1; ++e) {
            int s = colt[e];                                  // wave-uniform
            float4 p = pt[e];                                 // wave-uniform 16B
            float xv = x[(size_t)s * 64 + lane];              // coalesced 256B
            S0 += p.x; S1 += p.y; S2 += p.z; S3 += p.w;
            z0 = fmaf(p.x, xv, z0);
            z1 = fmaf(p.y, xv, z1);
            z2 = fmaf(p.z, xv, z2);
            z3 = fmaf(p.w, xv, z3);
        }
        size_t zb = (size_t)(n - n0) * 1024 + t * 256 + lane;
        float v0 = z0 / S0, v1 = z1 / S1, v2 = z2 / S2, v3 = z3 / S3;
        ushort_t h0 = f2bf(v0), h1 = f2bf(v1), h2 = f2bf(v2), h3 = f2bf(v3);
        zh[zb]       = h0;  zl[zb]       = f2bf(v0 - bf2f(h0));
        zh[zb + 64]  = h1;  zl[zb + 64]  = f2bf(v1 - bf2f(h1));
        zh[zb + 128] = h2;  zl[zb + 128] = f2bf(v2 - bf2f(h2));
        zh[zb + 192] = h3;  zl[zb + 192] = f2bf(v3 - bf2f(h3));
    }
}

// ---------------------------------------------------------------------------
extern "C" void kernel_launch(void* const* d_in, const int* in_sizes, int n_in,
                              void* d_out, int out_size, void* d_ws, size_t ws_size,
                              hipStream_t stream) {
    const float* fm    = (const float*)d_in[0];
    const float* emb   = (const float*)d_in[1];
    const float* lin_w = (const float*)d_in[2];
    const float* lin_b = (const float*)d_in[3];
    const float* ln_g  = (const float*)d_in[4];
    const float* ln_b  = (const float*)d_in[5];
    const float* Wsrc  = (const float*)d_in[6];
    const float* Wdst  = (const float*)d_in[7];
    const float* asrc  = (const float*)d_in[8];
    const float* adst  = (const float*)d_in[9];
    const float* cbias = (const float*)d_in[10];
    const int*   ei    = (const int*)d_in[11];
    float* out = (float*)d_out;
    (void)in_sizes; (void)n_in; (void)out_size;

    char* w = (char*)d_ws;
    size_t off = 0;
    auto alloc = [&](size_t bytes) -> void* {
        void* p = w + off;
        off += (bytes + 255) & ~(size_t)255;
        return p;
    };
    ushort_t* wcTh = (ushort_t*)alloc((size_t)LL * 64 * 64 * 2);
    ushort_t* wcTl = (ushort_t*)alloc((size_t)LL * 64 * 64 * 2);
    ushort_t* lwTh = (ushort_t*)alloc((size_t)64 * 256 * 2);
    ushort_t* lwTl = (ushort_t*)alloc((size_t)64 * 256 * 2);
    ushort_t* bpTh = (ushort_t*)alloc((size_t)LL * 64 * 1024 * 2);
    ushort_t* bpTl = (ushort_t*)alloc((size_t)LL * 64 * 1024 * 2);
    float* bsum    = (float*)alloc((size_t)LL * 64 * 4);
    int*   row_ptr = (int*)  alloc((size_t)TT * (NN + 1) * 4);
    int*   cursor  = (int*)  alloc((size_t)TT * NN * 4);
    int*   colarr  = (int*)  alloc((size_t)TT * EPN * 4);
    int*   dstarr  = (int*)  alloc((size_t)TT * EPN * 4);
    float* parr    = (float*)alloc((size_t)TT * EPN * 4 * 4);
    int*   csum    = (int*)  alloc((size_t)TT * NCH * 4);
    int*   cbase   = (int*)  alloc((size_t)TT * NCH * 4);
    float* x       = (float*)alloc(N64 * 4);
    float* xnew    = (float*)alloc(N64 * 4);
    float* s_all   = (float*)alloc(N64 * 4);
    float* ybuf    = (float*)alloc(N64 * 4);
    // rotating z chunk: CHK rows x K=1024, split-bf16 planes (~102.8 MB)
    size_t planeE = (size_t)CHK * 1024;
    ushort_t* zh = (ushort_t*)alloc(2 * planeE * 2);
    ushort_t* zl = zh + planeE;

    hipMemsetAsync(cursor, 0, (size_t)TT * NN * 4, stream);
    k_prep<<<512, 256, 0, stream>>>(Wsrc, Wdst, asrc, adst, cbias, lin_w,
                                    wcTh, wcTl, lwTh, lwTl, bpTh, bpTl, bsum);
    k_hist<<<(TT * EE + 255) / 256, 256, 0, stream>>>(ei, cursor);
    k_scan1<<<TT * NCH, 256, 0, stream>>>(cursor, csum);
    k_scan2<<<1, 64, 0, stream>>>(csum, cbase, row_ptr);
    k_scan3<<<TT * NCH, 256, 0, stream>>>(cursor, cbase, row_ptr);
    k_scatter<<<(TT * EPN + 255) / 256, 256, 0, stream>>>(ei, cursor, colarr, dstarr);

    const int GB = (NN + 127) / 128;   // 782 blocks (128 rows each)
    // feature transform: GEMM K=256 with fp32 A (split fused into staging)
    k_gemm_mx<8><<<GB, 256, 0, stream>>>((const ushort_t*)fm, nullptr,
                                         lwTh, lwTl, 256, 256, NN,
                                         nullptr, ybuf);
    k_feat_post<<<NN / 4, 256, 0, stream>>>(ybuf, lin_b, ln_g, ln_b, emb, x);

    const dim3 gp((EPN + 255) / 256, TT);
    for (int l = 0; l < LL; ++l) {
        const float* xin = (l == 0) ? x : xnew;
        float* dest = (l == 0) ? xnew : out;
        // collapsed attention-logit projection: s_all = xin @ wcoll_l  [N,64]
        k_gemm_mx<8><<<GB, 256, 0, stream>>>((const ushort_t*)xin, nullptr,
                                             wcTh + l * 4096, wcTl + l * 4096,
                                             64, 64, NN, nullptr, s_all);
        // edge-parallel p = exp(leaky(logit)) for all types of this layer
        k_edgep<<<gp, 256, 0, stream>>>(s_all, colarr, dstarr, parr);
        const ushort_t* Bh = bpTh + (size_t)l * 65536;
        const ushort_t* Bl = bpTl + (size_t)l * 65536;
        for (int n0 = 0; n0 < NN; n0 += CHK) {
            int n1 = (n0 + CHK < NN) ? n0 + CHK : NN;
            int nr = n1 - n0;
            k_edge2<<<(nr + 3) / 4, 256, 0, stream>>>(xin, parr, row_ptr, colarr,
                                                      zh, zl, n0, n1);
            // chunk GEMM: full K=1024, gelu((v+bias)/4) epilogue, direct write
            k_gemm_mx<2><<<(nr + 127) / 128, 256, 0, stream>>>(
                zh, zl, Bh, Bl, 1024, 1024, nr, bsum + l * 64, dest + (size_t)n0 * 64);
        }
    }
}

// Round 3
// 1023.615 us; speedup vs baseline: 1.0912x; 1.0912x over previous
//
#include <hip/hip_runtime.h>
#include <hip/hip_bf16.h>
#include <cstdint>

#define NN   100000
#define TT   4
#define EE   250000
#define LL   2
#define NCH  49            // ceil(NN/2048)
#define EPN  (EE + NN)     // 350000
#define N64  ((size_t)NN * 64)

typedef unsigned short ushort_t;
typedef __attribute__((ext_vector_type(8))) short bf16x8;
typedef __attribute__((ext_vector_type(16))) float floatx16;

static __device__ __forceinline__ float gelu_exact(float v) {
    return 0.5f * v * (1.0f + erff(v * 0.7071067811865476f));
}
static __device__ __forceinline__ float wave_sum64(float v) {
    #pragma unroll
    for (int m = 32; m; m >>= 1) v += __shfl_xor(v, m, 64);
    return v;
}
// fp32 -> bf16 round-to-nearest-even (finite inputs only)
static __device__ __forceinline__ ushort_t f2bf(float f) {
    unsigned u = __float_as_uint(f);
    u += 0x7FFFu + ((u >> 16) & 1u);
    return (ushort_t)(u >> 16);
}
static __device__ __forceinline__ float bf2f(ushort_t h) {
    return __uint_as_float((unsigned)h << 16);
}
// async global->LDS 16B (per-lane global addr; LDS dest = wave base + lane*16)
static __device__ __forceinline__ void gl_lds16(const ushort_t* g, ushort_t* l) {
    __builtin_amdgcn_global_load_lds(
        (const __attribute__((address_space(1))) void*)g,
        (__attribute__((address_space(3))) void*)l, 16, 0, 0);
}

// ---------------------------------------------------------------------------
// Prep: all GEMM B-operands as TRANSPOSED split-bf16 planes [n][k]:
//  wcollT[l][col][d]  (K=64)   col = t*8+side*4+h, from W·a dot products
//  linwT[c][k]        (K=256)  from lin_w[k][c]
//  bprojT[l][c][kidx] (K=1024) kidx = t*256+h*64+d, val 0.25*W_src[l,t,d,h*64+c]
//  bsum[l][c] = sum_t conv_bias
// ---------------------------------------------------------------------------
__global__ __launch_bounds__(256) void k_prep(
    const float* __restrict__ Wsrc, const float* __restrict__ Wdst,
    const float* __restrict__ asrc, const float* __restrict__ adst,
    const float* __restrict__ cb, const float* __restrict__ lin_w,
    ushort_t* __restrict__ wcTh, ushort_t* __restrict__ wcTl,
    ushort_t* __restrict__ lwTh, ushort_t* __restrict__ lwTl,
    ushort_t* __restrict__ bpTh, ushort_t* __restrict__ bpTl,
    float* __restrict__ bsum)
{
    int id = blockIdx.x * 256 + threadIdx.x;   // grid = 131072 exactly
    {   // bprojT: id = ((((l*4+t)*4+h)*64 + c)*64 + d)
        int d = id & 63;
        int c = (id >> 6) & 63;
        int h = (id >> 12) & 3;
        int t = (id >> 14) & 3;
        int l = (id >> 16) & 1;
        float v = 0.25f * Wsrc[(((l * 4 + t) * 64 + d) * 256) + h * 64 + c];
        int dst = (l * 64 + c) * 1024 + (t * 256 + h * 64 + d);
        ushort_t hh = f2bf(v);
        bpTh[dst] = hh;
        bpTl[dst] = f2bf(v - bf2f(hh));
    }
    if (id < LL * 64 * 64) {   // wcollT
        int d   = id & 63;
        int col = (id >> 6) & 63;
        int l   = (id >> 12) & 1;
        int t = col >> 3, side = (col >> 2) & 1, h = col & 3;
        const float* W = side ? Wdst : Wsrc;
        const float* a = side ? adst : asrc;
        int wb = ((l * 4 + t) * 64 + d) * 256 + h * 64;
        int ab = ((l * 4 + t) * 4 + h) * 64;
        float s = 0.f;
        #pragma unroll 8
        for (int c2 = 0; c2 < 64; ++c2) s = fmaf(W[wb + c2], a[ab + c2], s);
        int dst = (l * 64 + col) * 64 + d;
        ushort_t hh = f2bf(s);
        wcTh[dst] = hh;
        wcTl[dst] = f2bf(s - bf2f(hh));
    }
    if (id < 64 * 256) {       // linwT: c = id>>8, k = id&255
        int k = id & 255, c = id >> 8;
        float v = lin_w[k * 64 + c];
        ushort_t hh = f2bf(v);
        lwTh[c * 256 + k] = hh;
        lwTl[c * 256 + k] = f2bf(v - bf2f(hh));
    }
    if (id < LL * 64) {        // bias_sum
        int l = id >> 6, c = id & 63;
        float s = 0.f;
        for (int t = 0; t < TT; ++t) s += cb[(l * 4 + t) * 64 + c];
        bsum[id] = s;
    }
}

// ---------------------------------------------------------------------------
// CSR build; scatter writes packed (src,dst) int2 -> one dirty line per edge
// ---------------------------------------------------------------------------
__global__ void k_hist(const int* __restrict__ ei, int* __restrict__ cursor) {
    int id = blockIdx.x * 256 + threadIdx.x;
    if (id >= TT * EE) return;
    int t = id / EE, e = id - t * EE;
    int d = ei[(t * 2 + 1) * EE + e];
    atomicAdd(&cursor[t * NN + d], 1);
}

__global__ __launch_bounds__(256) void k_scan1(const int* __restrict__ deg,
                                               int* __restrict__ csum) {
    int b = blockIdx.x, t = b / NCH, cc = b - t * NCH;
    int tid = threadIdx.x;
    int base = cc * 2048 + tid * 8;
    int s = 0;
    #pragma unroll
    for (int i = 0; i < 8; ++i) {
        int idx = base + i;
        if (idx < NN) s += deg[t * NN + idx] + 1;   // +1: self loop
    }
    #pragma unroll
    for (int m = 32; m; m >>= 1) s += __shfl_xor(s, m, 64);
    __shared__ int ws4[4];
    int lane = tid & 63, wid = tid >> 6;
    if (lane == 0) ws4[wid] = s;
    __syncthreads();
    if (tid == 0) csum[b] = ws4[0] + ws4[1] + ws4[2] + ws4[3];
}

__global__ void k_scan2(const int* __restrict__ csum, int* __restrict__ cbase,
                        int* __restrict__ row_ptr) {
    int t = threadIdx.x;
    if (t >= TT) return;
    int base = 0;
    for (int c = 0; c < NCH; ++c) {
        cbase[t * NCH + c] = base;
        base += csum[t * NCH + c];
    }
    row_ptr[t * (NN + 1) + NN] = base;   // = EE + NN
}

__global__ __launch_bounds__(256) void k_scan3(int* __restrict__ cursor,
                                               const int* __restrict__ cbase,
                                               int* __restrict__ row_ptr) {
    int b = blockIdx.x, t = b / NCH, cc = b - t * NCH;
    int tid = threadIdx.x, lane = tid & 63, wid = tid >> 6;
    int base = cc * 2048 + tid * 8;
    int vals[8], ts = 0;
    #pragma unroll
    for (int i = 0; i < 8; ++i) {
        int idx = base + i;
        int v = (idx < NN) ? cursor[t * NN + idx] + 1 : 0;
        vals[i] = v; ts += v;
    }
    int v = ts;
    #pragma unroll
    for (int off = 1; off < 64; off <<= 1) {
        int u = __shfl_up(v, off, 64);
        if (lane >= off) v += u;
    }
    __shared__ int wt[4];
    if (lane == 63) wt[wid] = v;
    __syncthreads();
    int wbase = 0;
    for (int w = 0; w < wid; ++w) wbase += wt[w];
    int run = cbase[t * NCH + cc] + wbase + (v - ts);
    #pragma unroll
    for (int i = 0; i < 8; ++i) {
        int idx = base + i;
        if (idx < NN) {
            row_ptr[t * (NN + 1) + idx] = run;
            cursor[t * NN + idx] = run;     // becomes scatter write-head
        }
        run += vals[i];
    }
}

__global__ void k_scatter(const int* __restrict__ ei, int* __restrict__ cursor,
                          int2* __restrict__ sd) {
    int id = blockIdx.x * 256 + threadIdx.x;
    if (id >= TT * EPN) return;
    int t = id / EPN, r = id - t * EPN;
    int s, d;
    if (r < EE) { s = ei[t * 2 * EE + r]; d = ei[(t * 2 + 1) * EE + r]; }
    else        { s = d = r - EE; }
    int pos = atomicAdd(&cursor[t * NN + d], 1);
    sd[(size_t)t * EPN + pos] = make_int2(s, d);
}

// ---------------------------------------------------------------------------
// Split-bf16 MFMA GEMM: C[N,64] = A[N,K] @ B[K,64] via 3 products
// (ah·bh + al·bh + ah·bl), mfma_f32_32x32x16_bf16.
// LDS layout: linear 64B rows (LK=32 shorts), XOR chunk-swizzle on the
// GLOBAL source side:  LDS[r][c] = A[r][c ^ sg(r)],  sg(r)=(r^(r>>2))&3.
// bf16 path stages via global_load_lds width-16 (direct-to-LDS, linear dest);
// fp32 path (FLAGS&8) splits during staging via register writes.
// Fragment layouts (verified m74/m101/m120-lineage):
//   A[m][k]: m=lane&31, k=(lane>>5)*8+j    B[k][n]: n=lane&31, same k
//   C/D: col=lane&31 (+32*ct), row=(reg&3)+8*(reg>>2)+4*(lane>>5)
// FLAGS bit0: add accbuf; bit1: gelu((v+bias)*0.25); bit3: A is fp32
// ---------------------------------------------------------------------------
template <int FLAGS>
__global__ __launch_bounds__(256, 4) void k_gemm_mx(
    const ushort_t* __restrict__ Ahi, const ushort_t* __restrict__ Alo,
    const ushort_t* __restrict__ Bhi, const ushort_t* __restrict__ Blo,
    int K, int ldb, int nrows,
    const float* __restrict__ accbuf, const float* __restrict__ bias,
    float* __restrict__ Cout)
{
    constexpr int KC = 32;
    __shared__ ushort_t sAh[128 * 32], sAl[128 * 32];
    __shared__ ushort_t sBh[64 * 32],  sBl[64 * 32];
    const int tid = threadIdx.x;
    const int w = tid >> 6, ln = tid & 63;
    const int l31 = ln & 31, hl = ln >> 5;
    const int rowbase = blockIdx.x * 128;

    floatx16 accv[2];
    #pragma unroll
    for (int ct = 0; ct < 2; ++ct)
        #pragma unroll
        for (int r = 0; r < 16; ++r) accv[ct][r] = 0.f;

    for (int kc = 0; kc < K; kc += KC) {
        __syncthreads();
        // stage A: 128 rows x 32 k (4 chunks of 8 shorts), both planes
        #pragma unroll
        for (int i = 0; i < 2; ++i) {
            int f = tid + i * 256;           // 0..511
            int r = f >> 2, cg = f & 3;
            int row = rowbase + r;
            int sg = (r ^ (r >> 2)) & 3;
            if constexpr (FLAGS & 8) {
                // load global chunk cg, store to LDS slot cg^sg
                int sw = r * 32 + ((cg ^ sg) << 3);
                if (row < nrows) {
                    const float* Af = (const float*)Ahi;
                    size_t ga = (size_t)row * K + kc + cg * 8;
                    float4 v0 = *(const float4*)(Af + ga);
                    float4 v1 = *(const float4*)(Af + ga + 4);
                    float vf[8] = {v0.x, v0.y, v0.z, v0.w, v1.x, v1.y, v1.z, v1.w};
                    unsigned hu[8], lu[8];
                    #pragma unroll
                    for (int q = 0; q < 8; ++q) {
                        ushort_t hh = f2bf(vf[q]);
                        hu[q] = hh;
                        lu[q] = f2bf(vf[q] - bf2f(hh));
                    }
                    uint4 H = make_uint4(hu[0] | (hu[1] << 16), hu[2] | (hu[3] << 16),
                                         hu[4] | (hu[5] << 16), hu[6] | (hu[7] << 16));
                    uint4 L = make_uint4(lu[0] | (lu[1] << 16), lu[2] | (lu[3] << 16),
                                         lu[4] | (lu[5] << 16), lu[6] | (lu[7] << 16));
                    *(uint4*)&sAh[sw] = H;
                    *(uint4*)&sAl[sw] = L;
                } else {
                    *(uint4*)&sAh[sw] = make_uint4(0, 0, 0, 0);
                    *(uint4*)&sAl[sw] = make_uint4(0, 0, 0, 0);
                }
            } else {
                // direct-to-LDS: global chunk cg^sg -> linear LDS slot cg
                // (LDS dest bytes = wave_base + lane*16: r*64+cg*16 == ln*16 + base)
                int so = r * 32 + (cg << 3);
                size_t ga = (size_t)row * K + kc + ((cg ^ sg) << 3);
                if (row < nrows) {               // masked lanes: stale LDS, rows discarded
                    gl_lds16(Ahi + ga, &sAh[so]);
                    gl_lds16(Alo + ga, &sAl[so]);
                }
            }
        }
        // stage B: 64 n-rows x 32 k, both planes, direct-to-LDS
        {
            int r = tid >> 2, cg = tid & 3;
            int sg = (r ^ (r >> 2)) & 3;
            int so = r * 32 + (cg << 3);
            size_t gb = (size_t)r * ldb + kc + ((cg ^ sg) << 3);
            gl_lds16(Bhi + gb, &sBh[so]);
            gl_lds16(Blo + gb, &sBl[so]);
        }
        __syncthreads();
        const int arow = (w << 5) + l31;
        const int sga = (arow ^ (arow >> 2)) & 3;
        const int sgb = (l31 ^ (l31 >> 2)) & 3;   // same for row l31 and 32+l31
        #pragma unroll
        for (int s = 0; s < 2; ++s) {
            const int c0 = (s << 1) | hl;          // k-chunk index 0..3
            const int ka = (c0 ^ sga) << 3;
            const int kb = (c0 ^ sgb) << 3;
            bf16x8 ah  = *(const bf16x8*)&sAh[arow * 32 + ka];
            bf16x8 al  = *(const bf16x8*)&sAl[arow * 32 + ka];
            bf16x8 bh0 = *(const bf16x8*)&sBh[l31 * 32 + kb];
            bf16x8 bl0 = *(const bf16x8*)&sBl[l31 * 32 + kb];
            bf16x8 bh1 = *(const bf16x8*)&sBh[(32 + l31) * 32 + kb];
            bf16x8 bl1 = *(const bf16x8*)&sBl[(32 + l31) * 32 + kb];
            accv[0] = __builtin_amdgcn_mfma_f32_32x32x16_bf16(ah, bh0, accv[0], 0, 0, 0);
            accv[1] = __builtin_amdgcn_mfma_f32_32x32x16_bf16(ah, bh1, accv[1], 0, 0, 0);
            accv[0] = __builtin_amdgcn_mfma_f32_32x32x16_bf16(al, bh0, accv[0], 0, 0, 0);
            accv[1] = __builtin_amdgcn_mfma_f32_32x32x16_bf16(al, bh1, accv[1], 0, 0, 0);
            accv[0] = __builtin_amdgcn_mfma_f32_32x32x16_bf16(ah, bl0, accv[0], 0, 0, 0);
            accv[1] = __builtin_amdgcn_mfma_f32_32x32x16_bf16(ah, bl1, accv[1], 0, 0, 0);
        }
    }
    // epilogue
    #pragma unroll
    for (int ct = 0; ct < 2; ++ct) {
        int col = (ct << 5) + l31;
        float bv = (FLAGS & 2) ? bias[col] : 0.f;
        #pragma unroll
        for (int r = 0; r < 16; ++r) {
            int row = rowbase + (w << 5) + (r & 3) + ((r >> 2) << 3) + (hl << 2);
            if (row < nrows) {
                size_t idx = (size_t)row * 64 + col;
                float v = accv[ct][r];
                if (FLAGS & 1) v += accbuf[idx];
                if (FLAGS & 2) v = gelu_exact((v + bv) * 0.25f);
                Cout[idx] = v;
            }
        }
    }
}

// ---------------------------------------------------------------------------
// Feature epilogue: x = gelu(LN(y + lin_b)) + l2norm(emb)  (fp32 only)
// ---------------------------------------------------------------------------
__global__ __launch_bounds__(256) void k_feat_post(
    const float* __restrict__ y, const float* __restrict__ lin_b,
    const float* __restrict__ ln_g, const float* __restrict__ ln_b,
    const float* __restrict__ emb, float* __restrict__ xout)
{
    int n = (blockIdx.x << 2) + (threadIdx.x >> 6);
    int c = threadIdx.x & 63;
    size_t base = (size_t)n * 64 + c;
    float v = y[base] + lin_b[c];
    float mean = wave_sum64(v) * 0.015625f;
    float t = v - mean;
    float var = wave_sum64(t * t) * 0.015625f;
    float vn = t * (1.0f / sqrtf(var + 1e-5f)) * ln_g[c] + ln_b[c];
    float g = gelu_exact(vn);
    float e = emb[base];
    float nrm = sqrtf(wave_sum64(e * e));
    float xv = g + e / fmaxf(nrm, 1e-12f);
    xout[base] = xv;
}

// ---------------------------------------------------------------------------
// Edge-parallel softmax numerator: one lane = one CSR slot.
// p[t][e][h] = exp(leakyrelu(s_all[src][t*8+h] + s_all[dst][t*8+4+h]))
// ---------------------------------------------------------------------------
__global__ __launch_bounds__(256) void k_edgep(
    const float* __restrict__ s_all, const int2* __restrict__ sd,
    float* __restrict__ parr)
{
    int i = blockIdx.x * 256 + threadIdx.x;
    int t = blockIdx.y;
    if (i >= EPN) return;
    size_t base = (size_t)t * EPN + i;
    int2 e = sd[base];
    const float4 a = *(const float4*)&s_all[(size_t)e.x * 64 + t * 8];
    const float4 b = *(const float4*)&s_all[(size_t)e.y * 64 + t * 8 + 4];
    float l0 = a.x + b.x, l1 = a.y + b.y;
    float l2 = a.z + b.z, l3 = a.w + b.w;
    l0 = l0 > 0.f ? l0 : 0.2f * l0;
    l1 = l1 > 0.f ? l1 : 0.2f * l1;
    l2 = l2 > 0.f ? l2 : 0.2f * l2;
    l3 = l3 > 0.f ? l3 : 0.2f * l3;
    float4 p = make_float4(__expf(l0), __expf(l1), __expf(l2), __expf(l3));
    *(float4*)&parr[base * 4] = p;
}

// ---------------------------------------------------------------------------
// Edge aggregation for a TYPE PAIR (t0, t0+1) -> split-bf16 z planes [N][512].
// One wave per dst node; the two types run as interleaved independent streams
// to double the outstanding gather chains (latency-bound loop).
// z[n][tt*256+h*64+d] = (sum_e p_e,h * x[src_e,d]) / S[n,h]
// ---------------------------------------------------------------------------
__global__ __launch_bounds__(256) void k_edge2(
    const float* __restrict__ x, const float* __restrict__ parr,
    const int* __restrict__ row_ptr, const int2* __restrict__ sd,
    ushort_t* __restrict__ zh, ushort_t* __restrict__ zl, int t0)
{
    int n = (blockIdx.x << 2) + (threadIdx.x >> 6);   // grid = NN/4 exactly
    int lane = threadIdx.x & 63;
    const int tA = t0, tB = t0 + 1;
    int eA  = row_ptr[tA * (NN + 1) + n];
    int eA1 = row_ptr[tA * (NN + 1) + n + 1];
    int eB  = row_ptr[tB * (NN + 1) + n];
    int eB1 = row_ptr[tB * (NN + 1) + n + 1];
    const int2*   sdA = sd + (size_t)tA * EPN;
    const float4* pA  = (const float4*)parr + (size_t)tA * EPN;
    const int2*   sdB = sd + (size_t)tB * EPN;
    const float4* pB  = (const float4*)parr + (size_t)tB * EPN;
    float a0 = 0.f, a1 = 0.f, a2 = 0.f, a3 = 0.f;
    float SA0 = 0.f, SA1 = 0.f, SA2 = 0.f, SA3 = 0.f;
    float b0 = 0.f, b1 = 0.f, b2 = 0.f, b3 = 0.f;
    float SB0 = 0.f, SB1 = 0.f, SB2 = 0.f, SB3 = 0.f;
    int m = (eA1 - eA < eB1 - eB) ? (eA1 - eA) : (eB1 - eB);
    #pragma unroll 2
    for (int i = 0; i < m; ++i) {
        int sA_ = sdA[eA + i].x;                          // wave-uniform
        int sB_ = sdB[eB + i].x;
        float4 pa = pA[eA + i];                           // wave-uniform 16B
        float4 pb = pB[eB + i];
        float xa = x[(size_t)sA_ * 64 + lane];            // coalesced 256B
        float xb = x[(size_t)sB_ * 64 + lane];
        SA0 += pa.x; SA1 += pa.y; SA2 += pa.z; SA3 += pa.w;
        SB0 += pb.x; SB1 += pb.y; SB2 += pb.z; SB3 += pb.w;
        a0 = fmaf(pa.x, xa, a0); a1 = fmaf(pa.y, xa, a1);
        a2 = fmaf(pa.z, xa, a2); a3 = fmaf(pa.w, xa, a3);
        b0 = fmaf(pb.x, xb, b0); b1 = fmaf(pb.y, xb, b1);
        b2 = fmaf(pb.z, xb, b2); b3 = fmaf(pb.w, xb, b3);
    }
    eA += m; eB += m;
    for (; eA < eA1; ++eA) {
        int s = sdA[eA].x; float4 p = pA[eA];
        float xv = x[(size_t)s * 64 + lane];
        SA0 += p.x; SA1 += p.y; SA2 += p.z; SA3 += p.w;
        a0 = fmaf(p.x, xv, a0); a1 = fmaf(p.y, xv, a1);
        a2 = fmaf(p.z, xv, a2); a3 = fmaf(p.w, xv, a3);
    }
    for (; eB < eB1; ++eB) {
        int s = sdB[eB].x; float4 p = pB[eB];
        float xv = x[(size_t)s * 64 + lane];
        SB0 += p.x; SB1 += p.y; SB2 += p.z; SB3 += p.w;
        b0 = fmaf(p.x, xv, b0); b1 = fmaf(p.y, xv, b1);
        b2 = fmaf(p.z, xv, b2); b3 = fmaf(p.w, xv, b3);
    }
    size_t zb = (size_t)n * 512 + lane;
    {
        float v0 = a0 / SA0, v1 = a1 / SA1, v2 = a2 / SA2, v3 = a3 / SA3;
        ushort_t h0 = f2bf(v0), h1 = f2bf(v1), h2 = f2bf(v2), h3 = f2bf(v3);
        zh[zb]       = h0;  zl[zb]       = f2bf(v0 - bf2f(h0));
        zh[zb + 64]  = h1;  zl[zb + 64]  = f2bf(v1 - bf2f(h1));
        zh[zb + 128] = h2;  zl[zb + 128] = f2bf(v2 - bf2f(h2));
        zh[zb + 192] = h3;  zl[zb + 192] = f2bf(v3 - bf2f(h3));
    }
    {
        size_t zc = zb + 256;
        float v0 = b0 / SB0, v1 = b1 / SB1, v2 = b2 / SB2, v3 = b3 / SB3;
        ushort_t h0 = f2bf(v0), h1 = f2bf(v1), h2 = f2bf(v2), h3 = f2bf(v3);
        zh[zc]       = h0;  zl[zc]       = f2bf(v0 - bf2f(h0));
        zh[zc + 64]  = h1;  zl[zc + 64]  = f2bf(v1 - bf2f(h1));
        zh[zc + 128] = h2;  zl[zc + 128] = f2bf(v2 - bf2f(h2));
        zh[zc + 192] = h3;  zl[zc + 192] = f2bf(v3 - bf2f(h3));
    }
}

// ---------------------------------------------------------------------------
extern "C" void kernel_launch(void* const* d_in, const int* in_sizes, int n_in,
                              void* d_out, int out_size, void* d_ws, size_t ws_size,
                              hipStream_t stream) {
    const float* fm    = (const float*)d_in[0];
    const float* emb   = (const float*)d_in[1];
    const float* lin_w = (const float*)d_in[2];
    const float* lin_b = (const float*)d_in[3];
    const float* ln_g  = (const float*)d_in[4];
    const float* ln_b  = (const float*)d_in[5];
    const float* Wsrc  = (const float*)d_in[6];
    const float* Wdst  = (const float*)d_in[7];
    const float* asrc  = (const float*)d_in[8];
    const float* adst  = (const float*)d_in[9];
    const float* cbias = (const float*)d_in[10];
    const int*   ei    = (const int*)d_in[11];
    float* out = (float*)d_out;
    (void)in_sizes; (void)n_in; (void)out_size; (void)ws_size;

    char* w = (char*)d_ws;
    size_t off = 0;
    auto alloc = [&](size_t bytes) -> void* {
        void* p = w + off;
        off += (bytes + 255) & ~(size_t)255;
        return p;
    };
    ushort_t* wcTh = (ushort_t*)alloc((size_t)LL * 64 * 64 * 2);
    ushort_t* wcTl = (ushort_t*)alloc((size_t)LL * 64 * 64 * 2);
    ushort_t* lwTh = (ushort_t*)alloc((size_t)64 * 256 * 2);
    ushort_t* lwTl = (ushort_t*)alloc((size_t)64 * 256 * 2);
    ushort_t* bpTh = (ushort_t*)alloc((size_t)LL * 64 * 1024 * 2);
    ushort_t* bpTl = (ushort_t*)alloc((size_t)LL * 64 * 1024 * 2);
    float* bsum    = (float*)alloc((size_t)LL * 64 * 4);
    int*   row_ptr = (int*)  alloc((size_t)TT * (NN + 1) * 4);
    int*   cursor  = (int*)  alloc((size_t)TT * NN * 4);
    int2*  sdarr   = (int2*) alloc((size_t)TT * EPN * 8);
    float* parr    = (float*)alloc((size_t)TT * EPN * 4 * 4);
    int*   csum    = (int*)  alloc((size_t)TT * NCH * 4);
    int*   cbase   = (int*)  alloc((size_t)TT * NCH * 4);
    float* x       = (float*)alloc(N64 * 4);
    float* s_all   = (float*)alloc(N64 * 4);
    float* accB    = (float*)alloc(N64 * 4);
    // z split planes for one type pair: [N][512] hi + lo  (204.8 MB)
    size_t planeE = (size_t)NN * 512;
    ushort_t* zh = (ushort_t*)alloc(2 * planeE * 2);
    ushort_t* zl = zh + planeE;

    hipMemsetAsync(cursor, 0, (size_t)TT * NN * 4, stream);
    k_prep<<<512, 256, 0, stream>>>(Wsrc, Wdst, asrc, adst, cbias, lin_w,
                                    wcTh, wcTl, lwTh, lwTl, bpTh, bpTl, bsum);
    k_hist<<<(TT * EE + 255) / 256, 256, 0, stream>>>(ei, cursor);
    k_scan1<<<TT * NCH, 256, 0, stream>>>(cursor, csum);
    k_scan2<<<1, 64, 0, stream>>>(csum, cbase, row_ptr);
    k_scan3<<<TT * NCH, 256, 0, stream>>>(cursor, cbase, row_ptr);
    k_scatter<<<(TT * EPN + 255) / 256, 256, 0, stream>>>(ei, cursor, sdarr);

    const int GB = (NN + 127) / 128;   // 782 blocks (128 rows each)
    // feature transform: GEMM K=256 with fp32 A (split fused into staging)
    k_gemm_mx<8><<<GB, 256, 0, stream>>>((const ushort_t*)fm, nullptr,
                                         lwTh, lwTl, 256, 256, NN,
                                         nullptr, nullptr, accB);
    k_feat_post<<<NN / 4, 256, 0, stream>>>(accB, lin_b, ln_g, ln_b, emb, x);

    const dim3 gp((EPN + 255) / 256, TT);
    for (int l = 0; l < LL; ++l) {
        float* dest = (l == 0) ? x : out;
        // collapsed attention-logit projection: s_all = x @ wcoll_l  [N,64]
        k_gemm_mx<8><<<GB, 256, 0, stream>>>((const ushort_t*)x, nullptr,
                                             wcTh + l * 4096, wcTl + l * 4096,
                                             64, 64, NN, nullptr, nullptr, s_all);
        // edge-parallel p = exp(leaky(logit)) for all 4 types of this layer
        k_edgep<<<gp, 256, 0, stream>>>(s_all, sdarr, parr);
        const ushort_t* Bh = bpTh + (size_t)l * 65536;
        const ushort_t* Bl = bpTl + (size_t)l * 65536;
        // pair 0 (types 0,1): aggregate + GEMM K=512 -> accB
        k_edge2<<<NN / 4, 256, 0, stream>>>(x, parr, row_ptr, sdarr, zh, zl, 0);
        k_gemm_mx<0><<<GB, 256, 0, stream>>>(zh, zl, Bh, Bl, 512, 1024, NN,
                                             nullptr, nullptr, accB);
        // pair 1 (types 2,3): aggregate + GEMM K=512 + acc + gelu -> dest
        k_edge2<<<NN / 4, 256, 0, stream>>>(x, parr, row_ptr, sdarr, zh, zl, 2);
        k_gemm_mx<3><<<GB, 256, 0, stream>>>(zh, zl, Bh + 512, Bl + 512, 512, 1024,
                                             NN, accB, bsum + l * 64, dest);
    }
}